// Round 5
// baseline (244.242 us; speedup 1.0000x reference)
//
#include <hip/hip_runtime.h>

// SNN forward, all GEMM operands pre-swizzled to LDS-image order so every
// global_load_lds stages a contiguous 1 KB per wave (no gather).
//   Xt  [n][c 4][kk 8][tl 128][k 32]   f16   (t padded to 512, zeros)
//   W1t [ht 8][kk 8][hl 128][k 32]     f16 hi+lo
//   s1sw[mtile 250][kk 32][ml 128][hq 32] f16  (gemm2 A staging order)
//   W2t [kk 32][o 32][k 32]            f16 hi+lo
// f16 split-2: W = hi + lo, residual ~2^-24 => fp32-grade MFMA results.

#define NN 64
#define II 256
#define HH 1024
#define OO 18
#define TT 500

#define D_SR 0.9048374180359595f   // exp(-1/10)
#define C_SR 0.27182818284590454f  // e/10
#define D_RF 0.36787944117144233f  // exp(-1)
#define C_RF 2.718281828459045f    // e
#define THETA 10.0f
#define REFS (-20.0f)

typedef _Float16 f16;
typedef _Float16 f16x2 __attribute__((ext_vector_type(2)));
typedef _Float16 f16x8 __attribute__((ext_vector_type(8)));
typedef float f32x4 __attribute__((ext_vector_type(4)));

__device__ __forceinline__ void gl2lds16(const void* g, void* l) {
    __builtin_amdgcn_global_load_lds(
        (const __attribute__((address_space(1))) void*)g,
        (__attribute__((address_space(3))) void*)l, 16, 0, 0);
}

// ---------------- prep: X [N][I][T] f32 -> Xt tiled f16 ---------------------
// grid (4, 64) = (c, n); 256 thr; LDS transpose 128t x 128i per half.
__launch_bounds__(256)
__global__ void prep_xt(const float* __restrict__ X, f16* __restrict__ Xt) {
    __shared__ float tile[128 * 129];
    const int c = blockIdx.x, n = blockIdx.y;
    const int t0 = c * 128;
    const int tid = threadIdx.x;
    const int tx = tid & 63, rw = tid >> 6;
    const int q = tid & 3, tl6 = tid >> 2;  // tl6: 0..63

    for (int ih = 0; ih < 2; ++ih) {
        const float* Xn = X + ((size_t)n * II + ih * 128) * TT;
#pragma unroll 4
        for (int rep = 0; rep < 32; ++rep) {
            int r = rep * 4 + rw;
            int t = 2 * tx;
            float v0 = 0.f, v1 = 0.f;
            if (t0 + 128 <= TT) {
                float2 v = *(const float2*)(Xn + (size_t)r * TT + t0 + t);
                v0 = v.x; v1 = v.y;
            } else {
                if (t0 + t < TT)     v0 = Xn[(size_t)r * TT + t0 + t];
                if (t0 + t + 1 < TT) v1 = Xn[(size_t)r * TT + t0 + t + 1];
            }
            tile[t * 129 + r] = v0;
            tile[(t + 1) * 129 + r] = v1;
        }
        __syncthreads();
#pragma unroll
        for (int kkl = 0; kkl < 4; ++kkl)
#pragma unroll
            for (int hp = 0; hp < 2; ++hp) {
                int row = hp * 64 + tl6;
                f16x8 h;
#pragma unroll
                for (int e = 0; e < 8; ++e)
                    h[e] = (f16)tile[row * 129 + kkl * 32 + q * 8 + e];
                size_t dst = ((((size_t)(n * 4 + c) * 8 + ih * 4 + kkl) * 128 + row) * 32) + q * 8;
                *(f16x8*)(Xt + dst) = h;
            }
        __syncthreads();
    }
}

// ---------------- prep: W1 -> W1t hi/lo tiled -------------------------------
__launch_bounds__(256)
__global__ void prep_w1t(const float* __restrict__ W1, f16* __restrict__ Wh,
                         f16* __restrict__ Wl) {
    int idx = blockIdx.x * 256 + threadIdx.x;  // < 32768
    int q = idx & 3, hl = (idx >> 2) & 127, kk = (idx >> 9) & 7, ht = idx >> 12;
    const float* src = W1 + (size_t)(ht * 128 + hl) * II + kk * 32 + q * 8;
    f16x8 h, l;
#pragma unroll
    for (int e = 0; e < 8; ++e) {
        float w = src[e];
        f16 hh = (f16)w;
        h[e] = hh;
        l[e] = (f16)(w - (float)hh);
    }
    *(f16x8*)(Wh + (size_t)idx * 8) = h;
    *(f16x8*)(Wl + (size_t)idx * 8) = l;
}

// ---------------- prep: W2 -> W2t hi/lo tiled [kk][o 32][k 32] --------------
__launch_bounds__(256)
__global__ void prep_w2t(const float* __restrict__ W2, f16* __restrict__ Wh,
                         f16* __restrict__ Wl) {
    int idx = blockIdx.x * 256 + threadIdx.x;  // < 4096
    int q = idx & 3, o = (idx >> 2) & 31, kk = idx >> 7;
    f16x8 h, l;
#pragma unroll
    for (int e = 0; e < 8; ++e) {
        float w = (o < OO) ? W2[(size_t)o * HH + kk * 32 + q * 8 + e] : 0.f;
        f16 hh = (f16)w;
        h[e] = hh;
        l[e] = (f16)(w - (float)hh);
    }
    *(f16x8*)(Wh + (size_t)idx * 8) = h;
    *(f16x8*)(Wl + (size_t)idx * 8) = l;
}

// ---------------- FUSED layer 1: GEMM1 (split-f16 MFMA) + psp/spike scan ----
// grid (8, 64) = 512 blocks, 256 thr. Block = (n, 128-h tile); 4 t-chunks of
// 128. Staging is contiguous 1 KB per gl2lds. Pack writes s1 directly in
// gemm2's staging-tile order.
__launch_bounds__(256)
__global__ void gemm1_scan1(const f16* __restrict__ Xt, const f16* __restrict__ Wh,
                            const f16* __restrict__ Wl, f16* __restrict__ S1sw) {
    __shared__ __align__(16) char smem[128 * 129 * 4];  // 66,048 B
    f16* As = (f16*)smem;                // 8 KB
    f16* Bh = (f16*)(smem + 8192);       // 8 KB
    f16* Bl = (f16*)(smem + 16384);      // 8 KB
    float* yb = (float*)smem;            // 128 x 129 f32 (union)

    const int tid = threadIdx.x;
    const int wave = tid >> 6, lane = tid & 63;

    // XCD swizzle: the 8 h-tiles of one n share an XCD (f%8 fixed)
    const int f = blockIdx.y * 8 + blockIdx.x;
    const int x = f & 7, g = f >> 3;
    const int n = x * 8 + (g & 7);
    const int ht = g >> 3;
    const int h0g = ht * 128;

    const f16* Abase = Xt + (size_t)(n * 4) * 8 * 4096;
    const f16* Bhbase = Wh + (size_t)ht * 8 * 4096;
    const f16* Blbase = Wl + (size_t)ht * 8 * 4096;
    const int woff = wave * 1024 + lane * 8;  // element offset inside a tile

    f16* lA = As + wave * 1024;
    f16* lBh = Bh + wave * 1024;
    f16* lBl = Bl + wave * 1024;

    const int wm = wave & 1, wn = wave >> 1;
    const int fr = lane & 15, kq = lane >> 4;

    float p1 = 0.f, a1 = 0.f, p2 = 0.f, a2 = 0.f;  // scan state (tid<128)

    for (int c = 0; c < 4; ++c) {
        const int t0 = c * 128;
        const int TCe = (TT - t0 < 128) ? (TT - t0) : 128;

        f32x4 acc[4][4] = {};
        for (int kk = 0; kk < 8; ++kk) {
            const f16* a = Abase + (size_t)(c * 8 + kk) * 4096 + woff;
            const f16* bh = Bhbase + (size_t)kk * 4096 + woff;
            const f16* bl = Blbase + (size_t)kk * 4096 + woff;
            gl2lds16(a, lA);
            gl2lds16(a + 512, lA + 512);
            gl2lds16(bh, lBh);
            gl2lds16(bh + 512, lBh + 512);
            gl2lds16(bl, lBl);
            gl2lds16(bl + 512, lBl + 512);
            __syncthreads();

            f16x8 av[4], bhv[4], blv[4];
#pragma unroll
            for (int i = 0; i < 4; ++i) {
                av[i]  = *(const f16x8*)(As + (wm * 64 + i * 16 + fr) * 32 + kq * 8);
                bhv[i] = *(const f16x8*)(Bh + (wn * 64 + i * 16 + fr) * 32 + kq * 8);
                blv[i] = *(const f16x8*)(Bl + (wn * 64 + i * 16 + fr) * 32 + kq * 8);
            }
#pragma unroll
            for (int i = 0; i < 4; ++i)
#pragma unroll
                for (int j = 0; j < 4; ++j) {
                    acc[i][j] = __builtin_amdgcn_mfma_f32_16x16x32_f16(av[i], bhv[j], acc[i][j], 0, 0, 0);
                    acc[i][j] = __builtin_amdgcn_mfma_f32_16x16x32_f16(av[i], blv[j], acc[i][j], 0, 0, 0);
                }
            __syncthreads();
        }

        // acc -> yb (t-major, stride 129: scan reads conflict-free)
#pragma unroll
        for (int i = 0; i < 4; ++i)
#pragma unroll
            for (int j = 0; j < 4; ++j) {
                int tr = wm * 64 + i * 16 + kq * 4;
                int hc = wn * 64 + j * 16 + fr;
#pragma unroll
                for (int r = 0; r < 4; ++r)
                    yb[(tr + r) * 129 + hc] = acc[i][j][r];
            }
        __syncthreads();

        // sequential scan; 8-deep LDS prefetch ring
        if (tid < 128) {
            float rb_[8];
#pragma unroll
            for (int j = 0; j < 8; ++j) rb_[j] = yb[j * 129 + tid];
            int t = 0;
            for (; t + 8 <= TCe; t += 8) {
#pragma unroll
                for (int j = 0; j < 8; ++j) {
                    float xv = rb_[j];
                    int tn = t + j + 8;
                    rb_[j] = (tn < TCe) ? yb[tn * 129 + tid] : 0.f;
                    a1 = D_SR * (a1 + p1);
                    p1 = D_SR * p1 + xv;
                    float ut = C_SR * a1;
                    a2 = D_RF * (a2 + p2);
                    float u = ut + C_RF * a2;
                    float s = (u >= THETA) ? 1.0f : 0.0f;
                    p2 = D_RF * p2 + REFS * s;
                    yb[(t + j) * 129 + tid] = s;
                }
            }
            int rem = TCe - t;
#pragma unroll
            for (int j = 0; j < 8; ++j) {
                if (j < rem) {
                    float xv = rb_[j];
                    a1 = D_SR * (a1 + p1);
                    p1 = D_SR * p1 + xv;
                    float ut = C_SR * a1;
                    a2 = D_RF * (a2 + p2);
                    float u = ut + C_RF * a2;
                    float s = (u >= THETA) ? 1.0f : 0.0f;
                    p2 = D_RF * p2 + REFS * s;
                    yb[(t + j) * 129 + tid] = s;
                }
            }
        }
        __syncthreads();

        // pack f16 into gemm2 staging order
        const int rowq = tid >> 6;
#pragma unroll 4
        for (int pass = 0; pass < 32; ++pass) {
            int row = pass * 4 + rowq;
            if (row < TCe) {
                float v0 = yb[row * 129 + 2 * lane];
                float v1 = yb[row * 129 + 2 * lane + 1];
                int m = n * TT + t0 + row;
                int mtile = m >> 7, ml = m & 127;
                int h = h0g + 2 * lane;
                int kk2 = h >> 5, hq = h & 31;
                f16x2 h2 = {(f16)v0, (f16)v1};
                *(f16x2*)(S1sw + (((size_t)mtile * 32 + kk2) * 128 + ml) * 32 + hq) = h2;
            }
        }
        __syncthreads();
    }
}

// ---------------- GEMM2 (MFMA, split-f16): y2 = s1 * W2^T -------------------
// grid 250; 256 thr; tile 128 m x 32 o; K=1024, BK=32; contiguous staging.
__launch_bounds__(256)
__global__ void gemm2_mfma(const f16* __restrict__ S1sw, const f16* __restrict__ W2h,
                           const f16* __restrict__ W2l, float* __restrict__ Y2) {
    __shared__ __align__(16) f16 As[128 * 32];  // 8 KB
    __shared__ __align__(16) f16 Bh[32 * 32];   // 2 KB
    __shared__ __align__(16) f16 Bl[32 * 32];   // 2 KB

    const int tid = threadIdx.x;
    const int wave = tid >> 6, lane = tid & 63;
    const int m0 = blockIdx.x * 128;
    const int fr = lane & 15, kq = lane >> 4;

    f16* lA = As + wave * 1024;
    f16* lB = (wave < 2 ? Bh : Bl) + (wave & 1) * 512;

    f32x4 acc[2][2] = {};

    for (int kk = 0; kk < 32; ++kk) {
        const f16* a = S1sw + ((size_t)blockIdx.x * 32 + kk) * 4096 + wave * 1024 + lane * 8;
        gl2lds16(a, lA);
        gl2lds16(a + 512, lA + 512);
        const f16* bsrc = (wave < 2 ? W2h : W2l) + (size_t)kk * 1024 + (wave & 1) * 512 + lane * 8;
        gl2lds16(bsrc, lB);
        __syncthreads();

        f16x8 av[2], bhv[2], blv[2];
#pragma unroll
        for (int i = 0; i < 2; ++i) {
            av[i]  = *(const f16x8*)(As + (wave * 32 + i * 16 + fr) * 32 + kq * 8);
            bhv[i] = *(const f16x8*)(Bh + (i * 16 + fr) * 32 + kq * 8);
            blv[i] = *(const f16x8*)(Bl + (i * 16 + fr) * 32 + kq * 8);
        }
#pragma unroll
        for (int i = 0; i < 2; ++i)
#pragma unroll
            for (int j = 0; j < 2; ++j) {
                acc[i][j] = __builtin_amdgcn_mfma_f32_16x16x32_f16(av[i], bhv[j], acc[i][j], 0, 0, 0);
                acc[i][j] = __builtin_amdgcn_mfma_f32_16x16x32_f16(av[i], blv[j], acc[i][j], 0, 0, 0);
            }
        __syncthreads();
    }

#pragma unroll
    for (int i = 0; i < 2; ++i)
#pragma unroll
        for (int j = 0; j < 2; ++j) {
            int rbase = m0 + wave * 32 + i * 16 + kq * 4;
            int cc = j * 16 + fr;
            float* p = Y2 + (size_t)rbase * 32 + cc;
#pragma unroll
            for (int r = 0; r < 4; ++r)
                p[(size_t)r * 32] = acc[i][j][r];
        }
}

// ---------------- scan2: y2 [N*T][32] f32 -> out [N][O][T] ------------------
#define PF2 16
__launch_bounds__(64)
__global__ void scan2_k(const float* __restrict__ Y2, float* __restrict__ Out) {
    __shared__ float sb[OO * TT];
    const int n = blockIdx.x, lane = threadIdx.x;
    const float* y = Y2 + (size_t)n * TT * 32;
    const bool act = (lane < 32);

    float p1 = 0.f, a1 = 0.f, p2 = 0.f, a2 = 0.f;
    float buf[PF2];
#pragma unroll
    for (int j = 0; j < PF2; ++j) buf[j] = act ? y[j * 32 + lane] : 0.f;

    int t = 0;
    for (; t + PF2 <= TT; t += PF2) {
#pragma unroll
        for (int j = 0; j < PF2; ++j) {
            float x = buf[j];
            buf[j] = (act && t + j + PF2 < TT) ? y[(t + j + PF2) * 32 + lane] : 0.f;
            a1 = D_SR * (a1 + p1);
            p1 = D_SR * p1 + x;
            float ut = C_SR * a1;
            a2 = D_RF * (a2 + p2);
            float u = ut + C_RF * a2;
            float s = (u >= THETA) ? 1.0f : 0.0f;
            p2 = D_RF * p2 + REFS * s;
            if (lane < OO) sb[lane * TT + t + j] = s;
        }
    }
#pragma unroll
    for (int j = 0; j < PF2; ++j) {
        if (t + j < TT) {
            float x = buf[j];
            a1 = D_SR * (a1 + p1);
            p1 = D_SR * p1 + x;
            float ut = C_SR * a1;
            a2 = D_RF * (a2 + p2);
            float u = ut + C_RF * a2;
            float s = (u >= THETA) ? 1.0f : 0.0f;
            p2 = D_RF * p2 + REFS * s;
            if (lane < OO) sb[lane * TT + t + j] = s;
        }
    }
    __syncthreads();
    float* on = Out + (size_t)n * OO * TT;
    for (int e = lane; e < OO * TT; e += 64) on[e] = sb[e];
}

extern "C" void kernel_launch(void* const* d_in, const int* in_sizes, int n_in,
                              void* d_out, int out_size, void* d_ws, size_t ws_size,
                              hipStream_t stream) {
    const float* X  = (const float*)d_in[0];
    const float* W1 = (const float*)d_in[1];
    const float* W2 = (const float*)d_in[2];
    float* out = (float*)d_out;

    const size_t s_s1 = (size_t)250 * 32 * 128 * 32 * 2;  // 65,536,000
    const size_t s_Xt = (size_t)NN * 4 * 8 * 128 * 32 * 2; // 16,777,216
    const size_t s_W  = (size_t)8 * 8 * 128 * 32 * 2;      //    524,288 (x2)
    const size_t s_W2 = (size_t)32 * 32 * 32 * 2;          //     65,536 (x2)
    // + y2 4,096,000 => ~87.5 MB total

    char* w = (char*)d_ws;
    f16*   s1sw = (f16*)w;  w += s_s1;
    f16*   Xt   = (f16*)w;  w += s_Xt;
    f16*   W1h  = (f16*)w;  w += s_W;
    f16*   W1l  = (f16*)w;  w += s_W;
    f16*   W2h  = (f16*)w;  w += s_W2;
    f16*   W2l  = (f16*)w;  w += s_W2;
    float* y2   = (float*)w;

    prep_xt<<<dim3(4, NN), 256, 0, stream>>>(X, Xt);
    prep_w1t<<<128, 256, 0, stream>>>(W1, W1h, W1l);
    prep_w2t<<<16, 256, 0, stream>>>(W2, W2h, W2l);

    gemm1_scan1<<<dim3(8, NN), 256, 0, stream>>>(Xt, W1h, W1l, s1sw);

    gemm2_mfma<<<250, 256, 0, stream>>>(s1sw, W2h, W2l, y2);
    scan2_k<<<NN, 64, 0, stream>>>(y2, out);
}